// Round 1
// baseline (1120.647 us; speedup 1.0000x reference)
//
#include <hip/hip_runtime.h>

// Static float4 component access (folds to .x/.y/.z/.w after unroll; avoids
// runtime-indexed register arrays -> scratch).
#define F4E(v,i) ((i)==0?(v).x:((i)==1?(v).y:((i)==2?(v).z:(v).w)))

// ---------------------------------------------------------------------------
// Scatter-add: agg[dst] += x[src], F=16 features. 4 threads per edge.
__global__ __launch_bounds__(256) void k_scatter16(
    const float* __restrict__ x, const int* __restrict__ ei,
    float* __restrict__ agg, int E, int N)
{
    int tid = blockIdx.x * 256 + threadIdx.x;
    int e = tid >> 2, p = tid & 3;
    if (e >= E) return;
    int src = ei[e];
    int dst = ei[E + e];
    if ((unsigned)src >= (unsigned)N || (unsigned)dst >= (unsigned)N) return;
    float4 v = *reinterpret_cast<const float4*>(x + (size_t)src * 16 + p * 4);
    float* o = agg + (size_t)dst * 16 + p * 4;
    atomicAdd(o + 0, v.x);
    atomicAdd(o + 1, v.y);
    atomicAdd(o + 2, v.z);
    atomicAdd(o + 3, v.w);
}

// Scatter-add: F=32 features. 8 threads per edge.
__global__ __launch_bounds__(256) void k_scatter32(
    const float* __restrict__ x, const int* __restrict__ ei,
    float* __restrict__ agg, int E, int N)
{
    int tid = blockIdx.x * 256 + threadIdx.x;
    int e = tid >> 3, p = tid & 7;
    if (e >= E) return;
    int src = ei[e];
    int dst = ei[E + e];
    if ((unsigned)src >= (unsigned)N || (unsigned)dst >= (unsigned)N) return;
    float4 v = *reinterpret_cast<const float4*>(x + (size_t)src * 32 + p * 4);
    float* o = agg + (size_t)dst * 32 + p * 4;
    atomicAdd(o + 0, v.x);
    atomicAdd(o + 1, v.y);
    atomicAdd(o + 2, v.z);
    atomicAdd(o + 3, v.w);
}

// ---------------------------------------------------------------------------
// Layer 1: h1[n] = relu(agg[n] @ w_rel(16x32) + b + x[n] @ w_root(16x32))
__global__ __launch_bounds__(256) void k_layer1(
    const float* __restrict__ x, const float* __restrict__ agg,
    const float* __restrict__ wroot, const float* __restrict__ wrel,
    const float* __restrict__ bias, float* __restrict__ h1, int N)
{
    __shared__ float4 s_wr[128], s_wl[128], s_b[8];   // 16x32 each, bias 32
    int t = threadIdx.x;
    if (t < 128) {
        s_wr[t] = reinterpret_cast<const float4*>(wroot)[t];
        s_wl[t] = reinterpret_cast<const float4*>(wrel)[t];
    }
    if (t < 8) s_b[t] = reinterpret_cast<const float4*>(bias)[t];
    __syncthreads();

    int n = blockIdx.x * 256 + t;
    if (n >= N) return;
    const float4* xr = reinterpret_cast<const float4*>(x + (size_t)n * 16);
    const float4* ar = reinterpret_cast<const float4*>(agg + (size_t)n * 16);

    float4 acc[8];
#pragma unroll
    for (int jc = 0; jc < 8; ++jc) acc[jc] = s_b[jc];

    for (int kc = 0; kc < 4; ++kc) {
        float4 a4 = xr[kc];
        float4 g4 = ar[kc];
#pragma unroll
        for (int kk = 0; kk < 4; ++kk) {
            float a = F4E(a4, kk), g = F4E(g4, kk);
            int k = kc * 4 + kk;
#pragma unroll
            for (int jc = 0; jc < 8; ++jc) {
                float4 wr = s_wr[k * 8 + jc];
                float4 wl = s_wl[k * 8 + jc];
                acc[jc].x += a * wr.x + g * wl.x;
                acc[jc].y += a * wr.y + g * wl.y;
                acc[jc].z += a * wr.z + g * wl.z;
                acc[jc].w += a * wr.w + g * wl.w;
            }
        }
    }

    float4* o = reinterpret_cast<float4*>(h1 + (size_t)n * 32);
#pragma unroll
    for (int jc = 0; jc < 8; ++jc) {
        float4 v = acc[jc];
        v.x = fmaxf(v.x, 0.f); v.y = fmaxf(v.y, 0.f);
        v.z = fmaxf(v.z, 0.f); v.w = fmaxf(v.w, 0.f);
        o[jc] = v;
    }
}

// ---------------------------------------------------------------------------
// Layer 2: h2[n] = relu(agg2[n] @ w_rel(32x64) + b + h1[n] @ w_root(32x64))
__global__ __launch_bounds__(256) void k_layer2(
    const float* __restrict__ h1, const float* __restrict__ agg,
    const float* __restrict__ wroot, const float* __restrict__ wrel,
    const float* __restrict__ bias, float* __restrict__ h2, int N)
{
    __shared__ float4 s_wr[512], s_wl[512], s_b[16];  // 32x64 each, bias 64
    int t = threadIdx.x;
    for (int i = t; i < 512; i += 256) {
        s_wr[i] = reinterpret_cast<const float4*>(wroot)[i];
        s_wl[i] = reinterpret_cast<const float4*>(wrel)[i];
    }
    if (t < 16) s_b[t] = reinterpret_cast<const float4*>(bias)[t];
    __syncthreads();

    int n = blockIdx.x * 256 + t;
    if (n >= N) return;
    const float4* xr = reinterpret_cast<const float4*>(h1 + (size_t)n * 32);
    const float4* ar = reinterpret_cast<const float4*>(agg + (size_t)n * 32);

    float4 acc[16];
#pragma unroll
    for (int jc = 0; jc < 16; ++jc) acc[jc] = s_b[jc];

    for (int kc = 0; kc < 8; ++kc) {
        float4 a4 = xr[kc];
        float4 g4 = ar[kc];
#pragma unroll
        for (int kk = 0; kk < 4; ++kk) {
            float a = F4E(a4, kk), g = F4E(g4, kk);
            int k = kc * 4 + kk;
#pragma unroll
            for (int jc = 0; jc < 16; ++jc) {
                float4 wr = s_wr[k * 16 + jc];
                float4 wl = s_wl[k * 16 + jc];
                acc[jc].x += a * wr.x + g * wl.x;
                acc[jc].y += a * wr.y + g * wl.y;
                acc[jc].z += a * wr.z + g * wl.z;
                acc[jc].w += a * wr.w + g * wl.w;
            }
        }
    }

    float4* o = reinterpret_cast<float4*>(h2 + (size_t)n * 64);
#pragma unroll
    for (int jc = 0; jc < 16; ++jc) {
        float4 v = acc[jc];
        v.x = fmaxf(v.x, 0.f); v.y = fmaxf(v.y, 0.f);
        v.z = fmaxf(v.z, 0.f); v.w = fmaxf(v.w, 0.f);
        o[jc] = v;
    }
}

// ---------------------------------------------------------------------------
// Fused FC: out = relu(h2 @ fc1(64x32) + b1) @ fc2(32x16) + b2
__global__ __launch_bounds__(256) void k_fc(
    const float* __restrict__ h2,
    const float* __restrict__ f1w, const float* __restrict__ f1b,
    const float* __restrict__ f2w, const float* __restrict__ f2b,
    float* __restrict__ out, int N)
{
    __shared__ float4 s_f1[512];  // 64x32
    __shared__ float4 s_f2[128];  // 32x16
    __shared__ float4 s_b1[8], s_b2[4];
    int t = threadIdx.x;
    for (int i = t; i < 512; i += 256) s_f1[i] = reinterpret_cast<const float4*>(f1w)[i];
    if (t < 128) s_f2[t] = reinterpret_cast<const float4*>(f2w)[t];
    if (t < 8)  s_b1[t] = reinterpret_cast<const float4*>(f1b)[t];
    if (t < 4)  s_b2[t] = reinterpret_cast<const float4*>(f2b)[t];
    __syncthreads();

    int n = blockIdx.x * 256 + t;
    if (n >= N) return;
    const float4* hr = reinterpret_cast<const float4*>(h2 + (size_t)n * 64);

    float4 acc3[8];
#pragma unroll
    for (int jc = 0; jc < 8; ++jc) acc3[jc] = s_b1[jc];

    for (int kc = 0; kc < 16; ++kc) {
        float4 a4 = hr[kc];
#pragma unroll
        for (int kk = 0; kk < 4; ++kk) {
            float a = F4E(a4, kk);
            int k = kc * 4 + kk;
#pragma unroll
            for (int jc = 0; jc < 8; ++jc) {
                float4 w = s_f1[k * 8 + jc];
                acc3[jc].x += a * w.x; acc3[jc].y += a * w.y;
                acc3[jc].z += a * w.z; acc3[jc].w += a * w.w;
            }
        }
    }
#pragma unroll
    for (int jc = 0; jc < 8; ++jc) {
        acc3[jc].x = fmaxf(acc3[jc].x, 0.f); acc3[jc].y = fmaxf(acc3[jc].y, 0.f);
        acc3[jc].z = fmaxf(acc3[jc].z, 0.f); acc3[jc].w = fmaxf(acc3[jc].w, 0.f);
    }

    float4 acc4[4];
#pragma unroll
    for (int jc = 0; jc < 4; ++jc) acc4[jc] = s_b2[jc];
#pragma unroll
    for (int k = 0; k < 32; ++k) {
        float a = F4E(acc3[k >> 2], k & 3);
#pragma unroll
        for (int jc = 0; jc < 4; ++jc) {
            float4 w = s_f2[k * 4 + jc];
            acc4[jc].x += a * w.x; acc4[jc].y += a * w.y;
            acc4[jc].z += a * w.z; acc4[jc].w += a * w.w;
        }
    }

    float4* o = reinterpret_cast<float4*>(out + (size_t)n * 16);
#pragma unroll
    for (int jc = 0; jc < 4; ++jc) o[jc] = acc4[jc];
}

// ---------------------------------------------------------------------------
extern "C" void kernel_launch(void* const* d_in, const int* in_sizes, int n_in,
                              void* d_out, int out_size, void* d_ws, size_t ws_size,
                              hipStream_t stream)
{
    const float* x   = (const float*)d_in[0];
    const int*   ei  = (const int*)d_in[1];
    const float* wr1 = (const float*)d_in[2];
    const float* wl1 = (const float*)d_in[3];
    const float* b1  = (const float*)d_in[4];
    const float* wr2 = (const float*)d_in[5];
    const float* wl2 = (const float*)d_in[6];
    const float* b2  = (const float*)d_in[7];
    const float* f1w = (const float*)d_in[8];
    const float* f1b = (const float*)d_in[9];
    const float* f2w = (const float*)d_in[10];
    const float* f2b = (const float*)d_in[11];
    float* out = (float*)d_out;

    const int N = in_sizes[0] / 16;
    const int E = in_sizes[1] / 2;

    // Workspace layout (floats):
    //   agg2 : [0,        N*32)
    //   h1   : [N*32,     N*64)
    //   h2   : [N*64,     N*128)   -- agg1 (N*16) aliases the start of h2;
    //                                 agg1 is dead before h2 is written.
    float* ws   = (float*)d_ws;
    float* agg2 = ws;
    float* h1   = ws + (size_t)N * 32;
    float* h2   = ws + (size_t)N * 64;
    float* agg1 = h2;

    hipMemsetAsync(agg2, 0, (size_t)N * 32 * sizeof(float), stream);
    hipMemsetAsync(agg1, 0, (size_t)N * 16 * sizeof(float), stream);

    dim3 blk(256);
    int g_n  = (N + 255) / 256;
    int g_s1 = (E * 4 + 255) / 256;
    int g_s2 = (E * 8 + 255) / 256;

    k_scatter16<<<g_s1, blk, 0, stream>>>(x, ei, agg1, E, N);
    k_layer1  <<<g_n,  blk, 0, stream>>>(x, agg1, wr1, wl1, b1, h1, N);
    k_scatter32<<<g_s2, blk, 0, stream>>>(h1, ei, agg2, E, N);
    k_layer2  <<<g_n,  blk, 0, stream>>>(h1, agg2, wr2, wl2, b2, h2, N);
    k_fc      <<<g_n,  blk, 0, stream>>>(h2, f1w, f1b, f2w, f2b, out, N);
}

// Round 2
// 404.411 us; speedup vs baseline: 2.7711x; 2.7711x over previous
//
#include <hip/hip_runtime.h>

// Static float4 component access (folds to .x/.y/.z/.w after unroll).
#define F4E(v,i) ((i)==0?(v).x:((i)==1?(v).y:((i)==2?(v).z:(v).w)))

// ---------------------------------------------------------------------------
// CSR build step 1: degree histogram of dst.
__global__ __launch_bounds__(256) void k_hist(
    const int* __restrict__ ei, int* __restrict__ deg, int E, int N)
{
    int e = blockIdx.x * 256 + threadIdx.x;
    if (e >= E) return;
    int dst = ei[E + e];
    if ((unsigned)dst < (unsigned)N) atomicAdd(deg + dst, 1);
}

// CSR build step 2a: per-block scan. 1024 elements/block (256 thr x 4).
// Writes per-element exclusive prefix (local to block) and per-block sums.
__global__ __launch_bounds__(256) void k_scan1(
    const int* __restrict__ deg, int* __restrict__ rs, int* __restrict__ bsum, int N)
{
    __shared__ int s[256];
    int t = threadIdx.x;
    int base = blockIdx.x * 1024 + t * 4;
    int d0 = (base + 0 < N) ? deg[base + 0] : 0;
    int d1 = (base + 1 < N) ? deg[base + 1] : 0;
    int d2 = (base + 2 < N) ? deg[base + 2] : 0;
    int d3 = (base + 3 < N) ? deg[base + 3] : 0;
    int sum = d0 + d1 + d2 + d3;
    s[t] = sum;
    __syncthreads();
    for (int off = 1; off < 256; off <<= 1) {
        int v = (t >= off) ? s[t - off] : 0;
        __syncthreads();
        s[t] += v;
        __syncthreads();
    }
    int excl = s[t] - sum;
    if (base + 0 < N) rs[base + 0] = excl;
    if (base + 1 < N) rs[base + 1] = excl + d0;
    if (base + 2 < N) rs[base + 2] = excl + d0 + d1;
    if (base + 3 < N) rs[base + 3] = excl + d0 + d1 + d2;
    if (t == 255) bsum[blockIdx.x] = s[255];
}

// CSR build step 2b: scan the block sums (nb <= 256), in place -> exclusive.
__global__ __launch_bounds__(256) void k_scan2(int* __restrict__ bsum, int nb)
{
    __shared__ int s[256];
    int t = threadIdx.x;
    int v0 = (t < nb) ? bsum[t] : 0;
    s[t] = v0;
    __syncthreads();
    for (int off = 1; off < 256; off <<= 1) {
        int v = (t >= off) ? s[t - off] : 0;
        __syncthreads();
        s[t] += v;
        __syncthreads();
    }
    if (t < nb) bsum[t] = s[t] - v0;
}

// CSR build step 2c: add block offsets; produce row_start and cursor copy.
__global__ __launch_bounds__(256) void k_scan3(
    int* __restrict__ rs, const int* __restrict__ bsum,
    int* __restrict__ cursor, int N, int E)
{
    int i = blockIdx.x * 256 + threadIdx.x;
    if (i > N) return;
    if (i == N) { rs[N] = E; return; }
    int v = rs[i] + bsum[i >> 10];
    rs[i] = v;
    cursor[i] = v;
}

// CSR build step 3: bucket src indices by dst.
__global__ __launch_bounds__(256) void k_bucket(
    const int* __restrict__ ei, int* __restrict__ cursor,
    int* __restrict__ esrc, int E, int N)
{
    int e = blockIdx.x * 256 + threadIdx.x;
    if (e >= E) return;
    int src = ei[e];
    int dst = ei[E + e];
    if ((unsigned)dst >= (unsigned)N) return;
    int pos = atomicAdd(cursor + dst, 1);
    esrc[pos] = src;
}

// ---------------------------------------------------------------------------
// Gather-sum, F=16: 4 threads per node, each owns a float4 of the row.
__global__ __launch_bounds__(256) void k_gather16(
    const float* __restrict__ x, const int* __restrict__ rs,
    const int* __restrict__ esrc, float* __restrict__ agg, int N)
{
    int tid = blockIdx.x * 256 + threadIdx.x;
    int n = tid >> 2, p = tid & 3;
    if (n >= N) return;
    int s0 = rs[n], s1 = rs[n + 1];
    float4 acc = make_float4(0.f, 0.f, 0.f, 0.f);
    int e = s0;
    for (; e + 1 < s1; e += 2) {
        int src0 = esrc[e], src1 = esrc[e + 1];
        float4 v0 = *reinterpret_cast<const float4*>(x + (size_t)src0 * 16 + p * 4);
        float4 v1 = *reinterpret_cast<const float4*>(x + (size_t)src1 * 16 + p * 4);
        acc.x += v0.x + v1.x; acc.y += v0.y + v1.y;
        acc.z += v0.z + v1.z; acc.w += v0.w + v1.w;
    }
    if (e < s1) {
        int src0 = esrc[e];
        float4 v0 = *reinterpret_cast<const float4*>(x + (size_t)src0 * 16 + p * 4);
        acc.x += v0.x; acc.y += v0.y; acc.z += v0.z; acc.w += v0.w;
    }
    *reinterpret_cast<float4*>(agg + (size_t)n * 16 + p * 4) = acc;
}

// Gather-sum, F=32: 8 threads per node.
__global__ __launch_bounds__(256) void k_gather32(
    const float* __restrict__ x, const int* __restrict__ rs,
    const int* __restrict__ esrc, float* __restrict__ agg, int N)
{
    int tid = blockIdx.x * 256 + threadIdx.x;
    int n = tid >> 3, p = tid & 7;
    if (n >= N) return;
    int s0 = rs[n], s1 = rs[n + 1];
    float4 acc = make_float4(0.f, 0.f, 0.f, 0.f);
    int e = s0;
    for (; e + 1 < s1; e += 2) {
        int src0 = esrc[e], src1 = esrc[e + 1];
        float4 v0 = *reinterpret_cast<const float4*>(x + (size_t)src0 * 32 + p * 4);
        float4 v1 = *reinterpret_cast<const float4*>(x + (size_t)src1 * 32 + p * 4);
        acc.x += v0.x + v1.x; acc.y += v0.y + v1.y;
        acc.z += v0.z + v1.z; acc.w += v0.w + v1.w;
    }
    if (e < s1) {
        int src0 = esrc[e];
        float4 v0 = *reinterpret_cast<const float4*>(x + (size_t)src0 * 32 + p * 4);
        acc.x += v0.x; acc.y += v0.y; acc.z += v0.z; acc.w += v0.w;
    }
    *reinterpret_cast<float4*>(agg + (size_t)n * 32 + p * 4) = acc;
}

// ---------------------------------------------------------------------------
// Layer 1: h1[n] = relu(agg[n] @ w_rel(16x32) + b + x[n] @ w_root(16x32))
__global__ __launch_bounds__(256) void k_layer1(
    const float* __restrict__ x, const float* __restrict__ agg,
    const float* __restrict__ wroot, const float* __restrict__ wrel,
    const float* __restrict__ bias, float* __restrict__ h1, int N)
{
    __shared__ float4 s_wr[128], s_wl[128], s_b[8];   // 16x32 each, bias 32
    int t = threadIdx.x;
    if (t < 128) {
        s_wr[t] = reinterpret_cast<const float4*>(wroot)[t];
        s_wl[t] = reinterpret_cast<const float4*>(wrel)[t];
    }
    if (t < 8) s_b[t] = reinterpret_cast<const float4*>(bias)[t];
    __syncthreads();

    int n = blockIdx.x * 256 + t;
    if (n >= N) return;
    const float4* xr = reinterpret_cast<const float4*>(x + (size_t)n * 16);
    const float4* ar = reinterpret_cast<const float4*>(agg + (size_t)n * 16);

    float4 acc[8];
#pragma unroll
    for (int jc = 0; jc < 8; ++jc) acc[jc] = s_b[jc];

    for (int kc = 0; kc < 4; ++kc) {
        float4 a4 = xr[kc];
        float4 g4 = ar[kc];
#pragma unroll
        for (int kk = 0; kk < 4; ++kk) {
            float a = F4E(a4, kk), g = F4E(g4, kk);
            int k = kc * 4 + kk;
#pragma unroll
            for (int jc = 0; jc < 8; ++jc) {
                float4 wr = s_wr[k * 8 + jc];
                float4 wl = s_wl[k * 8 + jc];
                acc[jc].x += a * wr.x + g * wl.x;
                acc[jc].y += a * wr.y + g * wl.y;
                acc[jc].z += a * wr.z + g * wl.z;
                acc[jc].w += a * wr.w + g * wl.w;
            }
        }
    }

    float4* o = reinterpret_cast<float4*>(h1 + (size_t)n * 32);
#pragma unroll
    for (int jc = 0; jc < 8; ++jc) {
        float4 v = acc[jc];
        v.x = fmaxf(v.x, 0.f); v.y = fmaxf(v.y, 0.f);
        v.z = fmaxf(v.z, 0.f); v.w = fmaxf(v.w, 0.f);
        o[jc] = v;
    }
}

// ---------------------------------------------------------------------------
// Layer 2: h2[n] = relu(agg2[n] @ w_rel(32x64) + b + h1[n] @ w_root(32x64))
__global__ __launch_bounds__(256) void k_layer2(
    const float* __restrict__ h1, const float* __restrict__ agg,
    const float* __restrict__ wroot, const float* __restrict__ wrel,
    const float* __restrict__ bias, float* __restrict__ h2, int N)
{
    __shared__ float4 s_wr[512], s_wl[512], s_b[16];  // 32x64 each, bias 64
    int t = threadIdx.x;
    for (int i = t; i < 512; i += 256) {
        s_wr[i] = reinterpret_cast<const float4*>(wroot)[i];
        s_wl[i] = reinterpret_cast<const float4*>(wrel)[i];
    }
    if (t < 16) s_b[t] = reinterpret_cast<const float4*>(bias)[t];
    __syncthreads();

    int n = blockIdx.x * 256 + t;
    if (n >= N) return;
    const float4* xr = reinterpret_cast<const float4*>(h1 + (size_t)n * 32);
    const float4* ar = reinterpret_cast<const float4*>(agg + (size_t)n * 32);

    float4 acc[16];
#pragma unroll
    for (int jc = 0; jc < 16; ++jc) acc[jc] = s_b[jc];

    for (int kc = 0; kc < 8; ++kc) {
        float4 a4 = xr[kc];
        float4 g4 = ar[kc];
#pragma unroll
        for (int kk = 0; kk < 4; ++kk) {
            float a = F4E(a4, kk), g = F4E(g4, kk);
            int k = kc * 4 + kk;
#pragma unroll
            for (int jc = 0; jc < 16; ++jc) {
                float4 wr = s_wr[k * 16 + jc];
                float4 wl = s_wl[k * 16 + jc];
                acc[jc].x += a * wr.x + g * wl.x;
                acc[jc].y += a * wr.y + g * wl.y;
                acc[jc].z += a * wr.z + g * wl.z;
                acc[jc].w += a * wr.w + g * wl.w;
            }
        }
    }

    float4* o = reinterpret_cast<float4*>(h2 + (size_t)n * 64);
#pragma unroll
    for (int jc = 0; jc < 16; ++jc) {
        float4 v = acc[jc];
        v.x = fmaxf(v.x, 0.f); v.y = fmaxf(v.y, 0.f);
        v.z = fmaxf(v.z, 0.f); v.w = fmaxf(v.w, 0.f);
        o[jc] = v;
    }
}

// ---------------------------------------------------------------------------
// Fused FC: out = relu(h2 @ fc1(64x32) + b1) @ fc2(32x16) + b2
__global__ __launch_bounds__(256) void k_fc(
    const float* __restrict__ h2,
    const float* __restrict__ f1w, const float* __restrict__ f1b,
    const float* __restrict__ f2w, const float* __restrict__ f2b,
    float* __restrict__ out, int N)
{
    __shared__ float4 s_f1[512];  // 64x32
    __shared__ float4 s_f2[128];  // 32x16
    __shared__ float4 s_b1[8], s_b2[4];
    int t = threadIdx.x;
    for (int i = t; i < 512; i += 256) s_f1[i] = reinterpret_cast<const float4*>(f1w)[i];
    if (t < 128) s_f2[t] = reinterpret_cast<const float4*>(f2w)[t];
    if (t < 8)  s_b1[t] = reinterpret_cast<const float4*>(f1b)[t];
    if (t < 4)  s_b2[t] = reinterpret_cast<const float4*>(f2b)[t];
    __syncthreads();

    int n = blockIdx.x * 256 + t;
    if (n >= N) return;
    const float4* hr = reinterpret_cast<const float4*>(h2 + (size_t)n * 64);

    float4 acc3[8];
#pragma unroll
    for (int jc = 0; jc < 8; ++jc) acc3[jc] = s_b1[jc];

    for (int kc = 0; kc < 16; ++kc) {
        float4 a4 = hr[kc];
#pragma unroll
        for (int kk = 0; kk < 4; ++kk) {
            float a = F4E(a4, kk);
            int k = kc * 4 + kk;
#pragma unroll
            for (int jc = 0; jc < 8; ++jc) {
                float4 w = s_f1[k * 8 + jc];
                acc3[jc].x += a * w.x; acc3[jc].y += a * w.y;
                acc3[jc].z += a * w.z; acc3[jc].w += a * w.w;
            }
        }
    }
#pragma unroll
    for (int jc = 0; jc < 8; ++jc) {
        acc3[jc].x = fmaxf(acc3[jc].x, 0.f); acc3[jc].y = fmaxf(acc3[jc].y, 0.f);
        acc3[jc].z = fmaxf(acc3[jc].z, 0.f); acc3[jc].w = fmaxf(acc3[jc].w, 0.f);
    }

    float4 acc4[4];
#pragma unroll
    for (int jc = 0; jc < 4; ++jc) acc4[jc] = s_b2[jc];
#pragma unroll
    for (int k = 0; k < 32; ++k) {
        float a = F4E(acc3[k >> 2], k & 3);
#pragma unroll
        for (int jc = 0; jc < 4; ++jc) {
            float4 w = s_f2[k * 4 + jc];
            acc4[jc].x += a * w.x; acc4[jc].y += a * w.y;
            acc4[jc].z += a * w.z; acc4[jc].w += a * w.w;
        }
    }

    float4* o = reinterpret_cast<float4*>(out + (size_t)n * 16);
#pragma unroll
    for (int jc = 0; jc < 4; ++jc) o[jc] = acc4[jc];
}

// ---------------------------------------------------------------------------
extern "C" void kernel_launch(void* const* d_in, const int* in_sizes, int n_in,
                              void* d_out, int out_size, void* d_ws, size_t ws_size,
                              hipStream_t stream)
{
    const float* x   = (const float*)d_in[0];
    const int*   ei  = (const int*)d_in[1];
    const float* wr1 = (const float*)d_in[2];
    const float* wl1 = (const float*)d_in[3];
    const float* b1  = (const float*)d_in[4];
    const float* wr2 = (const float*)d_in[5];
    const float* wl2 = (const float*)d_in[6];
    const float* b2  = (const float*)d_in[7];
    const float* f1w = (const float*)d_in[8];
    const float* f1b = (const float*)d_in[9];
    const float* f2w = (const float*)d_in[10];
    const float* f2b = (const float*)d_in[11];
    float* out = (float*)d_out;

    const int N = in_sizes[0] / 16;
    const int E = in_sizes[1] / 2;

    // Workspace layout (floats), 51.2 MB total (same footprint as round 1):
    //   agg2 : ws[0,        N*32)
    //   h1   : ws[N*32,     N*64)   -- deg/cursor (2N ints) alias h1 start;
    //                                  both dead before k_layer1 writes h1.
    //   h2   : ws[N*64,     N*128)  -- agg1 (N*16 f) aliases h2[0, N*16);
    //                                  esrc (E ints <= N*16) aliases
    //                                  h2[N*16, N*32); both dead before
    //                                  k_layer2 writes h2.
    //   row_start (N+1 ints) + bsum (128 ints) live in d_out scratch;
    //   k_fc overwrites all of d_out at the very end.
    float* ws   = (float*)d_ws;
    float* agg2 = ws;
    float* h1   = ws + (size_t)N * 32;
    float* h2   = ws + (size_t)N * 64;
    float* agg1 = h2;
    int*   esrc = (int*)(h2 + (size_t)N * 16);
    int*   deg    = (int*)h1;
    int*   cursor = (int*)h1 + N;
    int*   rs   = (int*)d_out;         // row_start, N+1 ints
    int*   bsum = (int*)d_out + N + 1; // block sums, <=128 ints

    hipMemsetAsync(deg, 0, (size_t)N * sizeof(int), stream);

    dim3 blk(256);
    int g_e  = (E + 255) / 256;
    int g_n  = (N + 255) / 256;
    int nb1  = (N + 1023) / 1024;           // scan level-1 blocks
    int g_s3 = (N + 1 + 255) / 256;
    int g_g1 = (N * 4 + 255) / 256;
    int g_g2 = (N * 8 + 255) / 256;

    k_hist   <<<g_e,  blk, 0, stream>>>(ei, deg, E, N);
    k_scan1  <<<nb1,  blk, 0, stream>>>(deg, rs, bsum, N);
    k_scan2  <<<1,    blk, 0, stream>>>(bsum, nb1);
    k_scan3  <<<g_s3, blk, 0, stream>>>(rs, bsum, cursor, N, E);
    k_bucket <<<g_e,  blk, 0, stream>>>(ei, cursor, esrc, E, N);

    k_gather16<<<g_g1, blk, 0, stream>>>(x, rs, esrc, agg1, N);
    k_layer1  <<<g_n,  blk, 0, stream>>>(x, agg1, wr1, wl1, b1, h1, N);
    k_gather32<<<g_g2, blk, 0, stream>>>(h1, rs, esrc, agg2, N);
    k_layer2  <<<g_n,  blk, 0, stream>>>(h1, agg2, wr2, wl2, b2, h2, N);
    k_fc      <<<g_n,  blk, 0, stream>>>(h2, f1w, f1b, f2w, f2b, out, N);
}